// Round 4
// baseline (78.672 us; speedup 1.0000x reference)
//
#include <hip/hip_runtime.h>

// BayesPosLinear: out[s,b,o] = sum_i input[s,b,i] * exp(w_mu[o,i] + (1e-6+softplus(w_std_eta[o,i]))*eps_w[b,o,i])
//                 + (b_mu[o] + (1e-6+softplus(b_std_eta[o]))*eps_b[b,o])
// plus KL(w), KL(b) scalars.
// S=16, B=32, IN=1024, OUT=1024.
//
// R4 structure:
//  - PREPASS (1024x256): sp[o,i] = softplus(w_eta)+1e-6 into d_ws (4MB), computed ONCE
//    (was 32x redundantly); both KL reductions fused here. ~2us.
//  - MAIN (512 blocks x 512 thr, 2 blocks/CU): input[b] (64KB) staged once in LDS.
//    wave = 4 og x 16 iq; each lane owns TWO o-rows -> each ds_read_b128 of input
//    feeds 8 FMAs (halves LDS return traffic vs R3).
//    Hand-written A/B double-buffered stream loads (6 dwordx4 in flight per buffer)
//    so HBM/L3 latency hides under the 16-s FMA body.
//  - Fallback (!PRE) path if ws_size < 4MB: sp computed inline + KL in main (R3 style).

constexpr int S_ = 16, B_ = 32, IN_ = 1024, OUT_ = 1024;

__device__ __forceinline__ float softplus_f(float x) {
    // stable for any x (b_eta straddles 0)
    float e = __expf(-fabsf(x));
    return fmaxf(x, 0.0f) + __logf(1.0f + e);
}

// ---------------- prepass: sp table + both KLs ----------------
__global__ __launch_bounds__(256) void bpl_pre_kernel(
    const float* __restrict__ w_mu, const float* __restrict__ w_eta,
    const float* __restrict__ b_mu, const float* __restrict__ b_eta,
    float* __restrict__ sp_out,   // [OUT,IN] = softplus(w_eta)+1e-6
    float* __restrict__ kl)       // kl[0]=kl_w, kl[1]=kl_b (pre-zeroed)
{
    __shared__ float red[4];
    const int tid  = threadIdx.x;
    const int wid  = tid >> 6;
    const int lane = tid & 63;

    const size_t base = (size_t)blockIdx.x * IN_ + tid * 4;
    const float4 mu = *reinterpret_cast<const float4*>(&w_mu[base]);
    const float4 et = *reinterpret_cast<const float4*>(&w_eta[base]);
    const float m[4] = {mu.x, mu.y, mu.z, mu.w};
    const float e[4] = {et.x, et.y, et.z, et.w};

    float sp[4];
    float local = 0.0f;
    #pragma unroll
    for (int j = 0; j < 4; ++j) {
        sp[j] = __logf(1.0f + __expf(e[j])) + 1e-6f;   // w_eta in [-4,-2] -> stable
        local += -__logf(sp[j]) + 0.5f * fmaf(sp[j], sp[j], m[j] * m[j]) - 0.5f;
    }
    float4 spv = {sp[0], sp[1], sp[2], sp[3]};
    *reinterpret_cast<float4*>(&sp_out[base]) = spv;

    #pragma unroll
    for (int off = 32; off > 0; off >>= 1) local += __shfl_xor(local, off, 64);
    if (lane == 0) red[wid] = local;
    __syncthreads();
    if (tid == 0) atomicAdd(&kl[0], red[0] + red[1] + red[2] + red[3]);

    if (blockIdx.x != 0) return;

    float lb = 0.0f;
    #pragma unroll
    for (int j = 0; j < 4; ++j) {
        const int idx = tid * 4 + j;
        const float sd = softplus_f(b_eta[idx]) + 1e-6f;
        const float mm = b_mu[idx];
        lb += -__logf(sd) + 0.5f * fmaf(sd, sd, mm * mm) - 0.5f;
    }
    #pragma unroll
    for (int off = 32; off > 0; off >>= 1) lb += __shfl_xor(lb, off, 64);
    __syncthreads();
    if (lane == 0) red[wid] = lb;
    __syncthreads();
    if (tid == 0) atomicAdd(&kl[1], red[0] + red[1] + red[2] + red[3]);
}

// ---------------- main kernel helpers ----------------
template<bool PRE>
__device__ __forceinline__ void wgen4(const float4 sp, const float4 ep, const float4 mu,
                                      float w[4], bool dokl, float& klw)
{
    float s[4];
    if (PRE) {
        s[0] = sp.x; s[1] = sp.y; s[2] = sp.z; s[3] = sp.w;
    } else {
        s[0] = __logf(1.0f + __expf(sp.x)) + 1e-6f;   // here sp = w_eta (<0)
        s[1] = __logf(1.0f + __expf(sp.y)) + 1e-6f;
        s[2] = __logf(1.0f + __expf(sp.z)) + 1e-6f;
        s[3] = __logf(1.0f + __expf(sp.w)) + 1e-6f;
    }
    const float epv[4] = {ep.x, ep.y, ep.z, ep.w};
    const float muv[4] = {mu.x, mu.y, mu.z, mu.w};
    #pragma unroll
    for (int j = 0; j < 4; ++j) {
        w[j] = __expf(fmaf(s[j], epv[j], muv[j]));
        if (!PRE && dokl)
            klw += -__logf(s[j]) + 0.5f * fmaf(s[j], s[j], muv[j] * muv[j]) - 0.5f;
    }
}

__device__ __forceinline__ void fma16(const float* __restrict__ smem, int off,
                                      const float w0[4], const float w1[4],
                                      float acc0[16], float acc1[16])
{
    #pragma unroll
    for (int s = 0; s < 16; ++s) {
        const float4 v = *reinterpret_cast<const float4*>(&smem[s * 1024 + off]);
        acc0[s] = fmaf(v.x, w0[0], acc0[s]);
        acc0[s] = fmaf(v.y, w0[1], acc0[s]);
        acc0[s] = fmaf(v.z, w0[2], acc0[s]);
        acc0[s] = fmaf(v.w, w0[3], acc0[s]);
        acc1[s] = fmaf(v.x, w1[0], acc1[s]);
        acc1[s] = fmaf(v.y, w1[1], acc1[s]);
        acc1[s] = fmaf(v.z, w1[2], acc1[s]);
        acc1[s] = fmaf(v.w, w1[3], acc1[s]);
    }
}

// ---------------- main batched-linear kernel ----------------
// grid: 512 blocks (8 xcd * 2 ohi * 32 b), 512 threads (8 waves).
// wave = 4 og x 16 iq; lane owns o0=o_base+wid*8+og*2 and o0+1.
template<bool PRE>
__global__ __launch_bounds__(512, 4) void bpl_main_kernel(
    const float* __restrict__ input,   // [S,B,IN]
    const float* __restrict__ w_mu,    // [OUT,IN]
    const float* __restrict__ w_sp,    // PRE ? sp table : w_eta
    const float* __restrict__ b_mu,    // [OUT]
    const float* __restrict__ b_eta,   // [OUT]
    const float* __restrict__ eps_w,   // [B,OUT,IN]
    const float* __restrict__ eps_b,   // [B,OUT]
    float* __restrict__ out,           // [S,B,OUT]
    float* __restrict__ kl)
{
    __shared__ float smem[16384];      // 64KB input[s][i]; overlaid by res[16][66] + kl partials after sync

    const int blk  = blockIdx.x;
    const int xcd  = blk & 7;
    const int rest = blk >> 3;
    const int b    = rest & 31;
    const int ohi  = rest >> 5;
    const int o_base = (xcd * 2 + ohi) * 64;

    const int tid  = threadIdx.x;
    const int wid  = tid >> 6;
    const int lane = tid & 63;
    const int og   = lane >> 4;        // 0..3
    const int iq   = lane & 15;        // 0..15
    const int o0   = o_base + wid * 8 + og * 2;

    // ---- stage input[b] into LDS ----
    {
        const int s = tid >> 5, c = tid & 31;
        const float* __restrict__ src = input + ((size_t)s * B_ + b) * IN_;
        float* dst = smem + s * 1024;
        #pragma unroll
        for (int j = 0; j < 8; ++j) {
            const int i = c * 4 + j * 128;
            *reinterpret_cast<float4*>(&dst[i]) =
                *reinterpret_cast<const float4*>(&src[i]);
        }
    }
    __syncthreads();

    const float* __restrict__ mu_r0 = w_mu + (size_t)o0 * IN_;
    const float* __restrict__ mu_r1 = mu_r0 + IN_;
    const float* __restrict__ sp_r0 = w_sp + (size_t)o0 * IN_;
    const float* __restrict__ sp_r1 = sp_r0 + IN_;
    const float* __restrict__ ep_r0 = eps_w + ((size_t)b * OUT_ + o0) * IN_;
    const float* __restrict__ ep_r1 = ep_r0 + IN_;

    const bool do_kl = (!PRE) && (b == 0);
    float klw = 0.0f;

    float acc0[16], acc1[16];
    #pragma unroll
    for (int s = 0; s < 16; ++s) { acc0[s] = 0.0f; acc1[s] = 0.0f; }

    const int ib = iq * 4;             // lane offset within a 64-float chunk

    float4 Amu0, Asp0, Aep0, Amu1, Asp1, Aep1;
    float4 Bmu0, Bsp0, Bep0, Bmu1, Bsp1, Bep1;

#define BPL_LOAD(P, IT) do { const int i_ = (IT) * 64 + ib;                               \
        P##mu0 = *reinterpret_cast<const float4*>(mu_r0 + i_);                            \
        P##sp0 = *reinterpret_cast<const float4*>(sp_r0 + i_);                            \
        P##ep0 = *reinterpret_cast<const float4*>(ep_r0 + i_);                            \
        P##mu1 = *reinterpret_cast<const float4*>(mu_r1 + i_);                            \
        P##sp1 = *reinterpret_cast<const float4*>(sp_r1 + i_);                            \
        P##ep1 = *reinterpret_cast<const float4*>(ep_r1 + i_); } while (0)

#define BPL_COMPUTE(P, IT) do {                                                           \
        float w0_[4], w1_[4];                                                             \
        wgen4<PRE>(P##sp0, P##ep0, P##mu0, w0_, do_kl, klw);                              \
        wgen4<PRE>(P##sp1, P##ep1, P##mu1, w1_, do_kl, klw);                              \
        fma16(smem, (IT) * 64 + ib, w0_, w1_, acc0, acc1); } while (0)

    BPL_LOAD(A, 0);
    #pragma unroll
    for (int itp = 0; itp < 8; ++itp) {
        const int itA = itp * 2, itB = itA + 1;
        BPL_LOAD(B, itB);
        BPL_COMPUTE(A, itA);
        if (itp < 7) BPL_LOAD(A, itA + 2);
        BPL_COMPUTE(B, itB);
    }
#undef BPL_LOAD
#undef BPL_COMPUTE

    // ---- reduce across the 16-lane iq group (4 butterfly steps) ----
    #pragma unroll
    for (int s = 0; s < 16; ++s) {
        float v = acc0[s];
        v += __shfl_xor(v, 1, 16); v += __shfl_xor(v, 2, 16);
        v += __shfl_xor(v, 4, 16); v += __shfl_xor(v, 8, 16);
        acc0[s] = v;
        v = acc1[s];
        v += __shfl_xor(v, 1, 16); v += __shfl_xor(v, 2, 16);
        v += __shfl_xor(v, 4, 16); v += __shfl_xor(v, 8, 16);
        acc1[s] = v;
    }
    // lane iq keeps s=iq for both o-rows (static cndmask chains)
    float r0 = acc0[0], r1 = acc1[0];
    #pragma unroll
    for (int s = 1; s < 16; ++s) {
        r0 = (iq == s) ? acc0[s] : r0;
        r1 = (iq == s) ? acc1[s] : r1;
    }

    if (do_kl) {
        #pragma unroll
        for (int off = 32; off > 0; off >>= 1) klw += __shfl_xor(klw, off, 64);
    }

    __syncthreads();                   // input LDS reads done; overlay

    const int col = wid * 8 + og * 2;
    smem[iq * 66 + col]     = r0;
    smem[iq * 66 + col + 1] = r1;
    if (do_kl && lane == 0) smem[1100 + wid] = klw;

    if (!PRE && blk == 0) {            // kl_b
        float klb = 0.0f;
        #pragma unroll
        for (int h = 0; h < 2; ++h) {
            const int oo = tid + h * 512;
            const float sd = softplus_f(b_eta[oo]) + 1e-6f;
            const float mm = b_mu[oo];
            klb += -__logf(sd) + 0.5f * fmaf(sd, sd, mm * mm) - 0.5f;
        }
        #pragma unroll
        for (int off = 32; off > 0; off >>= 1) klb += __shfl_xor(klb, off, 64);
        if (lane == 0) smem[1110 + wid] = klb;
    }
    __syncthreads();

    // ---- coalesced stores with fused bias ----
    {
        const int s = tid >> 5, c = tid & 31;
        #pragma unroll
        for (int h = 0; h < 2; ++h) {
            const int ol = c + h * 32;
            const int oo = o_base + ol;
            const float bias = fmaf(softplus_f(b_eta[oo]) + 1e-6f,
                                    eps_b[(size_t)b * OUT_ + oo], b_mu[oo]);
            out[((size_t)s * B_ + b) * OUT_ + oo] = smem[s * 66 + ol] + bias;
        }
    }

    if (!PRE && do_kl && tid == 0) {
        float t = 0.0f;
        #pragma unroll
        for (int k = 0; k < 8; ++k) t += smem[1100 + k];
        atomicAdd(&kl[0], t);
    }
    if (!PRE && blk == 0 && tid == 64) {
        float t = 0.0f;
        #pragma unroll
        for (int k = 0; k < 8; ++k) t += smem[1110 + k];
        atomicAdd(&kl[1], t);
    }
}

extern "C" void kernel_launch(void* const* d_in, const int* in_sizes, int n_in,
                              void* d_out, int out_size, void* d_ws, size_t ws_size,
                              hipStream_t stream)
{
    const float* input = (const float*)d_in[0];
    const float* w_mu  = (const float*)d_in[1];
    const float* w_eta = (const float*)d_in[2];
    const float* b_mu  = (const float*)d_in[3];
    const float* b_eta = (const float*)d_in[4];
    const float* eps_w = (const float*)d_in[5];
    const float* eps_b = (const float*)d_in[6];

    float* out = (float*)d_out;
    float* kl  = out + (size_t)S_ * B_ * OUT_;   // offsets 524288, 524289

    hipMemsetAsync(kl, 0, 2 * sizeof(float), stream);

    const size_t SP_BYTES = (size_t)OUT_ * IN_ * sizeof(float);
    if (ws_size >= SP_BYTES) {
        float* sp = (float*)d_ws;
        bpl_pre_kernel<<<1024, 256, 0, stream>>>(w_mu, w_eta, b_mu, b_eta, sp, kl);
        bpl_main_kernel<true><<<512, 512, 0, stream>>>(input, w_mu, sp, b_mu, b_eta,
                                                       eps_w, eps_b, out, kl);
    } else {
        bpl_main_kernel<false><<<512, 512, 0, stream>>>(input, w_mu, w_eta, b_mu, b_eta,
                                                        eps_w, eps_b, out, kl);
    }
}